// Round 6
// baseline (3194.175 us; speedup 1.0000x reference)
//
#include <hip/hip_runtime.h>

typedef __attribute__((ext_vector_type(8))) short bf16x8;
typedef __attribute__((ext_vector_type(4))) float f32x4;

#define DEVINL __device__ __forceinline__

constexpr int BATCH = 16384;
constexpr int DIN   = 1024;
constexpr int DHID  = 2048;
constexpr int NEXP  = 16;
constexpr int EXPSZ = 512;
constexpr int NPAIR = BATCH * 3;

DEVINL float bf2f(unsigned short v) {
  union { unsigned u; float f; } x; x.u = ((unsigned)v) << 16; return x.f;
}
DEVINL unsigned short f2bfbits(float f) {   // round-to-nearest-even bf16
  union { float f; unsigned u; } x; x.f = f;
  unsigned r = x.u + 0x7fff + ((x.u >> 16) & 1);
  return (unsigned short)(r >> 16);
}

DEVINL void gl2lds(const unsigned short* src, char* ldst) {
  __builtin_amdgcn_global_load_lds((const __attribute__((address_space(1))) void*)src,
                                   (__attribute__((address_space(3))) void*)ldst, 16, 0, 0);
}

// ---------------------------------------------------------------------------
// Split-bf16 MFMA GEMM, 128x128 tile, 4 waves (2x2 of 64x64), 16x16x32 bf16.
// B pre-split into BLEV bf16 arrays Bt[N][K], staged to LDS via
// global_load_lds (fragment-contiguous: unit u (16B) = g*128 + row, holding
// elems [row][kt + g*8 .. +7]).
// A is NOT staged through LDS: each lane loads its own 8-element fragment
// directly from global (fp32 -> in-register split into ALEV bf16 levels, or
// bf16 passthrough). Terms a_i x b_j with i+j <= LMAX accumulate smallest
// first — identical arithmetic to the round-4/5 kernel.
// AMODE: 0 = linear fp32 rows      (encoder GEMM2)
//        1 = gather fp32 rows via pairRow (expert GEMM1)
//        2 = pair-linear bf16 rows (expert GEMM2)
//        3 = concat(embP,embR) fp32 (encoder GEMM1; Av=embP, Av2=embR)
// EPI:   0 = +bias -> fp32 Cf
//        1 = +bias, relu -> bf16 Cb
//        2 = +bias, *pairW -> bf16 Cb
// ---------------------------------------------------------------------------
template<int ALEV, int BLEV, int LMAX, int AMODE, int EPI, int BK>
__global__ __launch_bounds__(256, 3)
void mgemm_k(const void* __restrict__ Av, const void* __restrict__ Av2,
             const unsigned short* __restrict__ B0p,
             const unsigned short* __restrict__ B1p,
             const unsigned short* __restrict__ B2p,
             const float* __restrict__ biasb,
             float* __restrict__ Cf, unsigned short* __restrict__ Cb,
             const int* __restrict__ pairRow, const float* __restrict__ pairW,
             const int* __restrict__ counts, const int* __restrict__ offs,
             int M, int N, int K)
{
  constexpr int KG = BK / 8;
  constexpr int UNITS = 128 * KG;
  constexpr int ISS = UNITS / 256;
  constexpr int NKK = BK / 32;
  constexpr bool EXPERT = (AMODE == 1 || AMODE == 2);
  __shared__ char smem[BLEV * UNITS * 16];
  char* sB0 = smem;
  char* sB1 = smem + UNITS * 16;
  char* sB2 = smem + 2 * UNITS * 16;

  int Mloc = M, rowBase = 0;
  const unsigned short* b0 = B0p;
  const unsigned short* b1 = B1p;
  const unsigned short* b2 = B2p;
  const float* bias = biasb;
  if (EXPERT) {
    const int e = blockIdx.z;
    Mloc = counts[e];
    rowBase = offs[e];
    const size_t eo = (size_t)e * (size_t)K * N;
    b0 = B0p + eo;
    if (BLEV > 1) b1 = B1p + eo;
    if (BLEV > 2) b2 = B2p + eo;
    bias = biasb + (size_t)e * N;
  }
  const int tile0 = blockIdx.x * 128;
  if (tile0 >= Mloc) return;
  const int col0 = blockIdx.y * 128;
  const int tid = threadIdx.x;
  const int lane = tid & 63;
  const int wr = ((tid >> 6) >> 1) * 64;
  const int wc = ((tid >> 6) & 1) * 64;
  const int l15 = lane & 15;
  const int lg  = lane >> 4;          // fixed k-subgroup of this lane

  // B staging source row (fixed across K)
  const int srow = tid & 127;
  const size_t boff = (size_t)(col0 + srow) * K;

  // per-m A row offsets (element units)
  size_t aoff[4];
  #pragma unroll
  for (int m = 0; m < 4; ++m) {
    const int r = tile0 + wr + m * 16 + l15;
    if (AMODE == 0) {
      aoff[m] = (size_t)r * K;
    } else if (AMODE == 3) {
      aoff[m] = (size_t)r * 512;
    } else {
      int p = rowBase + r; p = p < NPAIR - 1 ? p : NPAIR - 1;
      if (AMODE == 1) aoff[m] = (size_t)pairRow[p] * K;
      else            aoff[m] = (size_t)p * K;
    }
  }

  f32x4 acc[4][4];
  #pragma unroll
  for (int m = 0; m < 4; ++m)
    #pragma unroll
    for (int n = 0; n < 4; ++n) acc[m][n] = f32x4{0.f, 0.f, 0.f, 0.f};

  for (int kt = 0; kt < K; kt += BK) {
    // issue B staging (async direct-to-LDS)
    #pragma unroll
    for (int it = 0; it < ISS; ++it) {
      const int uo = (it * 256 + (tid & 192)) * 16;   // wave-uniform LDS base
      const int ko = kt + (it * 2 + (tid >> 7)) * 8;
      gl2lds(b0 + boff + ko, sB0 + uo);
      if (BLEV > 1) gl2lds(b1 + boff + ko, sB1 + uo);
      if (BLEV > 2) gl2lds(b2 + boff + ko, sB2 + uo);
    }
    // load + split A fragments in-register (independent of LDS; pre-barrier)
    bf16x8 a0[NKK][4], a1[NKK][4], a2[NKK][4];
    #pragma unroll
    for (int kk = 0; kk < NKK; ++kk) {
      const int k0 = kt + (kk * 4 + lg) * 8;
      #pragma unroll
      for (int m = 0; m < 4; ++m) {
        if (AMODE == 2) {
          a0[kk][m] = *(const bf16x8*)((const unsigned short*)Av + aoff[m] + k0);
        } else {
          const float* s;
          if (AMODE == 3) s = (k0 < 512) ? ((const float*)Av + aoff[m] + k0)
                                         : ((const float*)Av2 + aoff[m] + (k0 - 512));
          else            s = (const float*)Av + aoff[m] + k0;
          const float4 x0 = *(const float4*)s;
          const float4 x1 = *(const float4*)(s + 4);
          const float vv[8] = {x0.x, x0.y, x0.z, x0.w, x1.x, x1.y, x1.z, x1.w};
          bf16x8 q0, q1, q2;
          #pragma unroll
          for (int j = 0; j < 8; ++j) {
            const unsigned short c0 = f2bfbits(vv[j]);
            q0[j] = (short)c0;
            if (ALEV > 1) {
              const float r1v = vv[j] - bf2f(c0);
              const unsigned short c1 = f2bfbits(r1v);
              q1[j] = (short)c1;
              if (ALEV > 2) q2[j] = (short)f2bfbits(r1v - bf2f(c1));
            }
          }
          a0[kk][m] = q0;
          if (ALEV > 1) a1[kk][m] = q1;
          if (ALEV > 2) a2[kk][m] = q2;
        }
      }
    }
    __syncthreads();
    #pragma unroll
    for (int kk = 0; kk < NKK; ++kk) {
      const int g = kk * 4 + lg;
      #pragma unroll
      for (int n = 0; n < 4; ++n) {
        const size_t off = (size_t)(g * 128 + wc + n * 16 + l15) * 16;
        const bf16x8 b0f = *(const bf16x8*)(sB0 + off);
        bf16x8 b1f, b2f;
        if (BLEV > 1) b1f = *(const bf16x8*)(sB1 + off);
        if (BLEV > 2) b2f = *(const bf16x8*)(sB2 + off);
        #pragma unroll
        for (int m = 0; m < 4; ++m) {
          // smallest-magnitude terms first
          if (ALEV > 2 && LMAX >= 2)
            acc[m][n] = __builtin_amdgcn_mfma_f32_16x16x32_bf16(a2[kk][m], b0f, acc[m][n], 0, 0, 0);
          if (ALEV > 1 && BLEV > 1 && LMAX >= 2)
            acc[m][n] = __builtin_amdgcn_mfma_f32_16x16x32_bf16(a1[kk][m], b1f, acc[m][n], 0, 0, 0);
          if (BLEV > 2 && LMAX >= 2)
            acc[m][n] = __builtin_amdgcn_mfma_f32_16x16x32_bf16(a0[kk][m], b2f, acc[m][n], 0, 0, 0);
          if (ALEV > 1 && LMAX >= 1)
            acc[m][n] = __builtin_amdgcn_mfma_f32_16x16x32_bf16(a1[kk][m], b0f, acc[m][n], 0, 0, 0);
          if (BLEV > 1 && LMAX >= 1)
            acc[m][n] = __builtin_amdgcn_mfma_f32_16x16x32_bf16(a0[kk][m], b1f, acc[m][n], 0, 0, 0);
          acc[m][n] = __builtin_amdgcn_mfma_f32_16x16x32_bf16(a0[kk][m], b0f, acc[m][n], 0, 0, 0);
        }
      }
    }
    __syncthreads();
  }

  // epilogue. C/D mapping: col = lane&15, row = (lane>>4)*4 + j  [m89-verified]
  #pragma unroll
  for (int n = 0; n < 4; ++n) {
    const int cn = col0 + wc + n * 16 + l15;
    const float bv = bias[cn];
    #pragma unroll
    for (int m = 0; m < 4; ++m) {
      const int r0 = wr + m * 16 + ((lane >> 4) << 2);
      #pragma unroll
      for (int j = 0; j < 4; ++j) {
        const int rm = tile0 + r0 + j;
        if (EXPERT && rm >= Mloc) continue;
        const float v = acc[m][n][j] + bv;
        const size_t ci = (size_t)(EXPERT ? (rowBase + rm) : rm) * N + cn;
        if (EPI == 0) {
          Cf[ci] = v;
        } else if (EPI == 1) {
          Cb[ci] = f2bfbits(fmaxf(v, 0.f));
        } else {
          Cb[ci] = f2bfbits(v * pairW[rowBase + rm]);
        }
      }
    }
  }
}

// ---------------------------------------------------------------------------
// fp32 vector GEMM (gate + towers). C = relu(A@B[t] + bias[t]), fp32.
// ---------------------------------------------------------------------------
template<bool RELU>
__global__ __launch_bounds__(256, 2)
void gemm32_k(const float* __restrict__ Av, const float* __restrict__ Bb,
              const float* __restrict__ biasb, float* __restrict__ Cv,
              const int* __restrict__ taskPtr, int M, int N, int K)
{
  __shared__ float As[16][128];
  __shared__ float Bs[16][128];
  const int t = *taskPtr;
  const float* Bw = Bb + (size_t)t * K * N;
  const float* bias = biasb + (size_t)t * N;
  const int tile0 = blockIdx.x * 128;
  const int col0 = blockIdx.y * 128;
  const int tid = threadIdx.x;
  const int am = tid >> 1, ak = (tid & 1) * 8;
  const int bk = tid >> 4, bn = (tid & 15) * 8;
  const int rg = (tid >> 4) * 8, cg = (tid & 15) * 8;
  const float* aptr = Av + (size_t)(tile0 + am) * K;

  float acc[8][8];
  #pragma unroll
  for (int i = 0; i < 8; ++i)
    #pragma unroll
    for (int j = 0; j < 8; ++j) acc[i][j] = 0.f;

  for (int kt = 0; kt < K; kt += 16) {
    {
      const float* src = aptr + kt + ak;
      float4 x0 = *reinterpret_cast<const float4*>(src);
      float4 x1 = *reinterpret_cast<const float4*>(src + 4);
      As[ak+0][am]=x0.x; As[ak+1][am]=x0.y; As[ak+2][am]=x0.z; As[ak+3][am]=x0.w;
      As[ak+4][am]=x1.x; As[ak+5][am]=x1.y; As[ak+6][am]=x1.z; As[ak+7][am]=x1.w;
    }
    {
      const float* bsrc = Bw + (size_t)(kt + bk) * N + (col0 + bn);
      float4 b0 = *reinterpret_cast<const float4*>(bsrc);
      float4 b1 = *reinterpret_cast<const float4*>(bsrc + 4);
      Bs[bk][bn+0]=b0.x; Bs[bk][bn+1]=b0.y; Bs[bk][bn+2]=b0.z; Bs[bk][bn+3]=b0.w;
      Bs[bk][bn+4]=b1.x; Bs[bk][bn+5]=b1.y; Bs[bk][bn+6]=b1.z; Bs[bk][bn+7]=b1.w;
    }
    __syncthreads();
    #pragma unroll
    for (int k = 0; k < 16; ++k) {
      float4 a0 = *reinterpret_cast<const float4*>(&As[k][rg]);
      float4 a1 = *reinterpret_cast<const float4*>(&As[k][rg + 4]);
      float4 c0 = *reinterpret_cast<const float4*>(&Bs[k][cg]);
      float4 c1 = *reinterpret_cast<const float4*>(&Bs[k][cg + 4]);
      const float a[8] = {a0.x,a0.y,a0.z,a0.w,a1.x,a1.y,a1.z,a1.w};
      const float b[8] = {c0.x,c0.y,c0.z,c0.w,c1.x,c1.y,c1.z,c1.w};
      #pragma unroll
      for (int i = 0; i < 8; ++i)
        #pragma unroll
        for (int j = 0; j < 8; ++j)
          acc[i][j] = fmaf(a[i], b[j], acc[i][j]);
    }
    __syncthreads();
  }
  #pragma unroll
  for (int i = 0; i < 8; ++i) {
    const int mr = tile0 + rg + i;
    #pragma unroll
    for (int j = 0; j < 8; ++j) {
      float v = acc[i][j] + bias[col0 + cg + j];
      if (RELU) v = fmaxf(v, 0.f);
      Cv[(size_t)mr * N + col0 + cg + j] = v;
    }
  }
}

// ---------------------------------------------------------------------------
// transpose+convert: src fp32 [z][R][C] -> LEV bf16 split levels, [z][C][R]
// ---------------------------------------------------------------------------
template<int LEV>
__global__ __launch_bounds__(256)
void transp_k(const float* __restrict__ src, unsigned short* __restrict__ d0,
              unsigned short* __restrict__ d1, unsigned short* __restrict__ d2,
              int R, int C)
{
  __shared__ float tle[32][33];
  const size_t bb = (size_t)blockIdx.z * R * C;
  const int r0 = blockIdx.x * 32, c0 = blockIdx.y * 32;
  const int x = threadIdx.x & 31, y = threadIdx.x >> 5;
  #pragma unroll
  for (int i = 0; i < 32; i += 8)
    tle[y + i][x] = src[bb + (size_t)(r0 + y + i) * C + (c0 + x)];
  __syncthreads();
  #pragma unroll
  for (int i = 0; i < 32; i += 8) {
    const float v = tle[x][y + i];
    const size_t di = bb + (size_t)(c0 + y + i) * R + (r0 + x);
    const unsigned short b0 = f2bfbits(v);
    d0[di] = b0;
    if (LEV > 1) {
      const float r1 = v - bf2f(b0);
      const unsigned short b1 = f2bfbits(r1);
      d1[di] = b1;
      if (LEV > 2) d2[di] = f2bfbits(r1 - bf2f(b1));
    }
  }
}

// ---------------------------------------------------------------------------
// In-place LayerNorm (+ optional relu) over fp32 rows of COLS.
// ---------------------------------------------------------------------------
template<int COLS, bool RELU>
__global__ __launch_bounds__(256)
void ln_k(float* __restrict__ x, const float* __restrict__ g, const float* __restrict__ b)
{
  constexpr int PER = COLS / 256;
  const size_t row = blockIdx.x;
  float* xr = x + row * COLS;
  float v[PER];
  float s = 0.f, s2 = 0.f;
  #pragma unroll
  for (int i = 0; i < PER; ++i) {
    v[i] = xr[threadIdx.x + i * 256];
    s += v[i];
    s2 += v[i] * v[i];
  }
  #pragma unroll
  for (int o = 1; o < 64; o <<= 1) { s += __shfl_xor(s, o); s2 += __shfl_xor(s2, o); }
  __shared__ float ss[4], ss2[4];
  const int w = threadIdx.x >> 6;
  if ((threadIdx.x & 63) == 0) { ss[w] = s; ss2[w] = s2; }
  __syncthreads();
  s  = ss[0] + ss[1] + ss[2] + ss[3];
  s2 = ss2[0] + ss2[1] + ss2[2] + ss2[3];
  const float mu = s * (1.f / COLS);
  const float var = s2 * (1.f / COLS) - mu * mu;
  const float rs = rsqrtf(var + 1e-5f);
  #pragma unroll
  for (int i = 0; i < PER; ++i) {
    const int c = threadIdx.x + i * 256;
    float y = (v[i] - mu) * rs * g[c] + b[c];
    if (RELU) y = fmaxf(y, 0.f);
    xr[c] = y;
  }
}

// ---------------------------------------------------------------------------
// gate: logits = relu-g @ gW2[t] + gb2[t]; top-3 softmax; NO global atomics.
// ---------------------------------------------------------------------------
__global__ __launch_bounds__(256)
void gate_topk_k(const float* __restrict__ g, const float* __restrict__ gW2,
                 const float* __restrict__ gb2, const int* __restrict__ taskPtr,
                 float* __restrict__ gatesOut, int* __restrict__ topkIdx,
                 float* __restrict__ topkW)
{
  const int t = *taskPtr;
  const float* W = gW2 + (size_t)t * 128 * 16;
  const float* bias = gb2 + (size_t)t * 16;
  const int lane = threadIdx.x & 63;
  const int row = blockIdx.x * 4 + (threadIdx.x >> 6);
  const float* gr = g + (size_t)row * 128;
  const int e = lane & 15;
  const int q = lane >> 4;
  float s = 0.f;
  for (int j = q * 32; j < q * 32 + 32; ++j) s = fmaf(gr[j], W[j * 16 + e], s);
  s += __shfl_xor(s, 16);
  s += __shfl_xor(s, 32);
  s += bias[e];
  float logits[16];
  #pragma unroll
  for (int i = 0; i < 16; ++i) logits[i] = __shfl(s, i);
  int i0 = 0; float v0 = logits[0];
  #pragma unroll
  for (int i = 1; i < 16; ++i) if (logits[i] > v0) { v0 = logits[i]; i0 = i; }
  int i1 = -1; float v1 = -3.4e38f;
  #pragma unroll
  for (int i = 0; i < 16; ++i) if (i != i0 && logits[i] > v1) { v1 = logits[i]; i1 = i; }
  int i2 = -1; float v2 = -3.4e38f;
  #pragma unroll
  for (int i = 0; i < 16; ++i) if (i != i0 && i != i1 && logits[i] > v2) { v2 = logits[i]; i2 = i; }
  const float ex1 = expf(v1 - v0);
  const float ex2 = expf(v2 - v0);
  const float inv = 1.f / (1.f + ex1 + ex2);
  const float p0 = inv, p1 = ex1 * inv, p2 = ex2 * inv;
  if (lane < 16) {
    const float gv = (lane == i0) ? p0 : (lane == i1) ? p1 : (lane == i2) ? p2 : 0.f;
    gatesOut[(size_t)row * 16 + lane] = gv;
  }
  if (lane == 0) {
    topkIdx[row * 3 + 0] = i0; topkIdx[row * 3 + 1] = i1; topkIdx[row * 3 + 2] = i2;
    topkW [row * 3 + 0] = p0; topkW [row * 3 + 1] = p1; topkW [row * 3 + 2] = p2;
  }
}

// per-chunk expert histogram (LDS atomics only)
__global__ __launch_bounds__(256)
void hist_k(const int* __restrict__ topkIdx, int* __restrict__ chunkCnt)
{
  __shared__ int lc[NEXP];
  if (threadIdx.x < NEXP) lc[threadIdx.x] = 0;
  __syncthreads();
  const int row = blockIdx.x * 256 + threadIdx.x;
  #pragma unroll
  for (int k = 0; k < 3; ++k) atomicAdd(&lc[topkIdx[row * 3 + k]], 1);
  __syncthreads();
  if (threadIdx.x < NEXP) chunkCnt[blockIdx.x * NEXP + threadIdx.x] = lc[threadIdx.x];
}

// serial scan: counts/offs per expert + per-chunk bases (2048 adds, ~µs)
__global__ void scanB_k(const int* __restrict__ chunkCnt, int* __restrict__ counts,
                        int* __restrict__ offs, int* __restrict__ chunkBase)
{
  if (threadIdx.x == 0) {
    int tot[NEXP];
    for (int e = 0; e < NEXP; ++e) tot[e] = 0;
    for (int c = 0; c < 64; ++c)
      for (int e = 0; e < NEXP; ++e) tot[e] += chunkCnt[c * NEXP + e];
    int a = 0;
    for (int e = 0; e < NEXP; ++e) { offs[e] = a; counts[e] = tot[e]; a += tot[e]; }
    for (int e = 0; e < NEXP; ++e) {
      int b = offs[e];
      for (int c = 0; c < 64; ++c) { chunkBase[c * NEXP + e] = b; b += chunkCnt[c * NEXP + e]; }
    }
  }
}

// fill pair lists: LDS-atomic within-chunk offsets + precomputed chunk base
__global__ __launch_bounds__(256)
void fill2_k(const int* __restrict__ topkIdx, const float* __restrict__ topkW,
             const int* __restrict__ chunkBase, int* __restrict__ pairRow,
             float* __restrict__ pairW, int* __restrict__ rowPos)
{
  __shared__ int lc[NEXP];
  if (threadIdx.x < NEXP) lc[threadIdx.x] = 0;
  __syncthreads();
  const int row = blockIdx.x * 256 + threadIdx.x;
  #pragma unroll
  for (int k = 0; k < 3; ++k) {
    const int e = topkIdx[row * 3 + k];
    const int lofs = atomicAdd(&lc[e], 1);
    const int pos = chunkBase[blockIdx.x * NEXP + e] + lofs;
    pairRow[pos] = row;
    pairW[pos] = topkW[row * 3 + k];
    rowPos[row * 3 + k] = pos;
  }
}

__global__ __launch_bounds__(256)
void mixreduce_k(const unsigned short* __restrict__ eo, const int* __restrict__ rowPos,
                 float* __restrict__ mix)
{
  const size_t row = blockIdx.x;
  const size_t p0 = rowPos[row * 3 + 0];
  const size_t p1 = rowPos[row * 3 + 1];
  const size_t p2 = rowPos[row * 3 + 2];
  for (int c = threadIdx.x; c < EXPSZ; c += 256) {
    mix[row * EXPSZ + c] = bf2f(eo[p0 * EXPSZ + c]) + bf2f(eo[p1 * EXPSZ + c])
                         + bf2f(eo[p2 * EXPSZ + c]);
  }
}

__global__ __launch_bounds__(256)
void tower3_k(const float* __restrict__ t2, const float* __restrict__ tW3,
              const float* __restrict__ tb3, const int* __restrict__ taskPtr,
              float* __restrict__ out)
{
  const int t = *taskPtr;
  const float* w = tW3 + (size_t)t * 128;
  const float bias = tb3[t];
  const int lane = threadIdx.x & 63;
  const int row = blockIdx.x * 4 + (threadIdx.x >> 6);
  const float* x = t2 + (size_t)row * 128;
  float s = fmaf(x[lane], w[lane], x[lane + 64] * w[lane + 64]);
  #pragma unroll
  for (int o = 1; o < 64; o <<= 1) s += __shfl_xor(s, o);
  if (lane == 0) out[row] = 1.f / (1.f + expf(-(s + bias)));
  if (blockIdx.x == 0 && threadIdx.x == 0) out[BATCH] = (float)t;
}

// ---------------------------------------------------------------------------
extern "C" void kernel_launch(void* const* d_in, const int* in_sizes, int n_in,
                              void* d_out, int out_size, void* d_ws, size_t ws_size,
                              hipStream_t stream)
{
  (void)in_sizes; (void)n_in; (void)out_size; (void)ws_size;
  const float* embP  = (const float*)d_in[0];
  const float* embR  = (const float*)d_in[1];
  const float* encW1 = (const float*)d_in[2];
  const float* encB1 = (const float*)d_in[3];
  const float* ln1g  = (const float*)d_in[4];
  const float* ln1b  = (const float*)d_in[5];
  const float* encW2 = (const float*)d_in[6];
  const float* encB2 = (const float*)d_in[7];
  const float* ln2g  = (const float*)d_in[8];
  const float* ln2b  = (const float*)d_in[9];
  const float* gW1   = (const float*)d_in[10];
  const float* gb1   = (const float*)d_in[11];
  const float* gW2   = (const float*)d_in[12];
  const float* gb2   = (const float*)d_in[13];
  const float* We1   = (const float*)d_in[14];
  const float* be1   = (const float*)d_in[15];
  const float* We2   = (const float*)d_in[16];
  const float* be2   = (const float*)d_in[17];
  const float* tW1   = (const float*)d_in[18];
  const float* tb1   = (const float*)d_in[19];
  const float* tW2   = (const float*)d_in[20];
  const float* tb2   = (const float*)d_in[21];
  const float* tW3   = (const float*)d_in[22];
  const float* tb3   = (const float*)d_in[23];
  const int* taskPtr = (const int*)d_in[24];

  float* out = (float*)d_out;
  char* ws = (char*)d_ws;
  const size_t MB = 1ull << 20;

  // Lifetime-aliased workspace (peak ~209 MB):
  //  [0,64):    feat fp32 -> mix[0,32), t1[32,48), t2[48,56)
  //  [64,192):  h fp32 -> We1t(2lev)[64,96), We2t(2lev)[96,112), e1b[112,160), eob[160,208)
  //  [192,204): W1t(3lev) -> W2t(3lev) -> gbuf[192,200)
  //  [208,~209): metadata
  float* feat = (float*)(ws);
  float* mix  = (float*)(ws);
  float* t1   = (float*)(ws + 32 * MB);
  float* t2v  = (float*)(ws + 48 * MB);
  float* h    = (float*)(ws + 64 * MB);
  unsigned short* We1t0 = (unsigned short*)(ws + 64 * MB);
  unsigned short* We1t1 = (unsigned short*)(ws + 80 * MB);
  unsigned short* We2t0 = (unsigned short*)(ws + 96 * MB);
  unsigned short* We2t1 = (unsigned short*)(ws + 104 * MB);
  unsigned short* e1b   = (unsigned short*)(ws + 112 * MB);
  unsigned short* eob   = (unsigned short*)(ws + 160 * MB);
  unsigned short* Wt0   = (unsigned short*)(ws + 192 * MB);  // W1t then W2t (4MB/level)
  unsigned short* Wt1   = (unsigned short*)(ws + 196 * MB);
  unsigned short* Wt2   = (unsigned short*)(ws + 200 * MB);
  float* gbuf = (float*)(ws + 192 * MB);
  char* small = ws + 208 * MB;
  int*   counts    = (int*)  (small);
  int*   offs      = (int*)  (small + 1024);
  int*   chunkCnt  = (int*)  (small + 2048);            // 64*16 ints = 4KB
  int*   chunkBase = (int*)  (small + 2048 + 4096);     // 4KB
  int*   topkIdx   = (int*)  (small + 16384);
  float* topkW     = (float*)(small + 16384 + 196608);
  int*   pairRow   = (int*)  (small + 16384 + 2 * 196608);
  float* pairW     = (float*)(small + 16384 + 3 * 196608);
  int*   rowPos    = (int*)  (small + 16384 + 4 * 196608);

  const dim3 blk(256, 1, 1);

  // encoder GEMM1: h = concat(embP,embR) @ W1 + b1  (triple-split, 6 terms)
  transp_k<3><<<dim3(DIN/32, DHID/32, 1), blk, 0, stream>>>(encW1, Wt0, Wt1, Wt2, DIN, DHID);
  mgemm_k<3,3,2,3,0,32><<<dim3(BATCH/128, DHID/128, 1), blk, 0, stream>>>(
      embP, embR, Wt0, Wt1, Wt2, encB1, h, nullptr,
      nullptr, nullptr, nullptr, nullptr, BATCH, DHID, DIN);
  ln_k<DHID, true><<<dim3(BATCH, 1, 1), blk, 0, stream>>>(h, ln1g, ln1b);

  // encoder GEMM2: feat = h @ W2 + b2  (triple-split, 6 terms)
  transp_k<3><<<dim3(DHID/32, DIN/32, 1), blk, 0, stream>>>(encW2, Wt0, Wt1, Wt2, DHID, DIN);
  mgemm_k<3,3,2,0,0,32><<<dim3(BATCH/128, DIN/128, 1), blk, 0, stream>>>(
      h, nullptr, Wt0, Wt1, Wt2, encB2, feat, nullptr,
      nullptr, nullptr, nullptr, nullptr, BATCH, DIN, DHID);
  ln_k<DIN, false><<<dim3(BATCH, 1, 1), blk, 0, stream>>>(feat, ln2g, ln2b);

  // gate (fp32 path on fp32 feat) — no global atomics anywhere
  gemm32_k<true><<<dim3(BATCH/128, 1, 1), blk, 0, stream>>>(
      feat, gW1, gb1, gbuf, taskPtr, BATCH, 128, DIN);
  gate_topk_k<<<dim3(BATCH/4, 1, 1), blk, 0, stream>>>(
      gbuf, gW2, gb2, taskPtr, out + BATCH + 1, topkIdx, topkW);
  hist_k<<<dim3(BATCH/256, 1, 1), blk, 0, stream>>>(topkIdx, chunkCnt);
  scanB_k<<<dim3(1, 1, 1), dim3(64, 1, 1), 0, stream>>>(chunkCnt, counts, offs, chunkBase);
  fill2_k<<<dim3(BATCH/256, 1, 1), blk, 0, stream>>>(topkIdx, topkW, chunkBase,
                                                     pairRow, pairW, rowPos);

  // expert weights, 2-level split (h region free now)
  transp_k<2><<<dim3(DIN/32, EXPSZ/32, NEXP), blk, 0, stream>>>(We1, We1t0, We1t1, nullptr, DIN, EXPSZ);
  transp_k<2><<<dim3(EXPSZ/32, EXPSZ/32, NEXP), blk, 0, stream>>>(We2, We2t0, We2t1, nullptr, EXPSZ, EXPSZ);

  // expert GEMM1: e1 = relu(feat[pairRow] @ We1[e] + be1)  (2x2 split, 3 terms)
  mgemm_k<2,2,1,1,1,32><<<dim3(BATCH/128, EXPSZ/128, NEXP), blk, 0, stream>>>(
      feat, nullptr, We1t0, We1t1, nullptr, be1, nullptr, e1b,
      pairRow, nullptr, counts, offs, NPAIR, EXPSZ, DIN);
  // expert GEMM2: eo = w_p * (e1 @ We2[e] + be2)  (A bf16, B split, 2 terms)
  mgemm_k<1,2,1,2,2,32><<<dim3(BATCH/128, EXPSZ/128, NEXP), blk, 0, stream>>>(
      e1b, nullptr, We2t0, We2t1, nullptr, be2, nullptr, eob,
      nullptr, pairW, counts, offs, NPAIR, EXPSZ, EXPSZ);
  mixreduce_k<<<dim3(BATCH, 1, 1), blk, 0, stream>>>(eob, rowPos, mix);

  // towers (fp32)
  gemm32_k<true><<<dim3(BATCH/128, 2, 1), blk, 0, stream>>>(
      mix, tW1, tb1, t1, taskPtr, BATCH, 256, EXPSZ);
  gemm32_k<true><<<dim3(BATCH/128, 1, 1), blk, 0, stream>>>(
      t1, tW2, tb2, t2v, taskPtr, BATCH, 128, 256);
  tower3_k<<<dim3(BATCH/4, 1, 1), blk, 0, stream>>>(t2v, tW3, tb3, taskPtr, out);
}

// Round 7
// 1427.194 us; speedup vs baseline: 2.2381x; 2.2381x over previous
//
#include <hip/hip_runtime.h>

typedef __attribute__((ext_vector_type(8))) _Float16 f16x8;
typedef __attribute__((ext_vector_type(4))) float f32x4;

#define DEVINL __device__ __forceinline__

constexpr int BATCH = 16384;
constexpr int DIN   = 1024;
constexpr int DHID  = 2048;
constexpr int NEXP  = 16;
constexpr int EXPSZ = 512;
constexpr int NPAIR = BATCH * 3;

DEVINL unsigned short f2h(float v) {
  _Float16 h = (_Float16)v;
  return __builtin_bit_cast(unsigned short, h);
}
DEVINL float h2f(unsigned short u) {
  return (float)__builtin_bit_cast(_Float16, u);
}

DEVINL void gl2lds(const unsigned short* src, char* ldst) {
  __builtin_amdgcn_global_load_lds((const __attribute__((address_space(1))) void*)src,
                                   (__attribute__((address_space(3))) void*)ldst, 16, 0, 0);
}

// ---------------------------------------------------------------------------
// fp16 split-MFMA GEMM, 128x128 tile, 4 waves (2x2 of 64x64), 16x16x32 f16.
// Round-5 structure: A reg-staged (fp32 -> fp16 level(s)) + ds_write into
// fragment-contiguous LDS; B pre-converted fp16 level arrays Bt[N][K] staged
// via global_load_lds. Unit u (16B) = g*128 + row -> elems [row][kt+g*8..+7].
// SPLIT=1 (fp32-grade): v = c0 + c1/2048 (c1 stored x2048 -> fp16 normal
//   range, immune to denorm flush). 3 MFMA terms: acc2 += a1'b0 + a0b1';
//   acc1 += a0b0; result = acc1 + acc2/2048. Residual ~2^-22 relative.
// SPLIT=0: plain 1-level fp16 (expert path).
// AMODE: 0 = linear fp32 rows      (encoder GEMM2)
//        1 = gather fp32 rows via pairRow (expert GEMM1)
//        2 = pair-linear fp16 rows (expert GEMM2)
//        3 = concat(embP,embR) fp32 (encoder GEMM1; Av=embP, Av2=embR)
// EPI:   0 = +bias -> fp32 Cf ; 1 = +bias,relu -> fp16 Cb ;
//        2 = +bias,*pairW -> fp16 Cb
// ---------------------------------------------------------------------------
template<int SPLIT, int AMODE, int EPI, int BK>
__global__ __launch_bounds__(256, SPLIT ? 2 : 3)
void mgemm_k(const void* __restrict__ Av, const void* __restrict__ Av2,
             const unsigned short* __restrict__ B0p,
             const unsigned short* __restrict__ B1p,
             const float* __restrict__ biasb,
             float* __restrict__ Cf, unsigned short* __restrict__ Cb,
             const int* __restrict__ pairRow, const float* __restrict__ pairW,
             const int* __restrict__ counts, const int* __restrict__ offs,
             int M, int N, int K)
{
  constexpr int KG = BK / 8;
  constexpr int UNITS = 128 * KG;
  constexpr int ISS = UNITS / 256;
  constexpr int NKK = BK / 32;
  constexpr int NARR = SPLIT ? 4 : 2;
  constexpr bool EXPERT = (AMODE == 1 || AMODE == 2);
  __shared__ char smem[NARR * UNITS * 16];
  char* sA0 = smem;
  char* sA1 = smem + UNITS * 16;                    // iff SPLIT
  char* sB0 = smem + (SPLIT ? 2 : 1) * UNITS * 16;
  char* sB1 = smem + 3 * UNITS * 16;                // iff SPLIT

  int Mloc = M, rowBase = 0;
  const unsigned short* b0 = B0p;
  const unsigned short* b1 = B1p;
  const float* bias = biasb;
  if (EXPERT) {
    const int e = blockIdx.z;
    Mloc = counts[e];
    rowBase = offs[e];
    const size_t eo = (size_t)e * (size_t)K * N;
    b0 = B0p + eo;
    if (SPLIT) b1 = B1p + eo;
    bias = biasb + (size_t)e * N;
  }
  const int tile0 = blockIdx.x * 128;
  if (tile0 >= Mloc) return;
  const int col0 = blockIdx.y * 128;
  const int tid = threadIdx.x;
  const int lane = tid & 63;
  const int wr = ((tid >> 6) >> 1) * 64;
  const int wc = ((tid >> 6) & 1) * 64;
  const int l15 = lane & 15;
  const int lg = lane >> 4;

  // per-thread staging row (fixed across K)
  const int srow = tid & 127;
  const float* aP = nullptr;
  const float* aR = nullptr;
  const float* aF = nullptr;
  const unsigned short* aH = nullptr;
  if (AMODE == 3) {
    aP = (const float*)Av  + (size_t)(tile0 + srow) * 512;
    aR = (const float*)Av2 + (size_t)(tile0 + srow) * 512;
  } else if (AMODE == 0) {
    aF = (const float*)Av + (size_t)(tile0 + srow) * K;
  } else if (AMODE == 1) {
    int p = rowBase + tile0 + srow; p = p < NPAIR - 1 ? p : NPAIR - 1;
    aF = (const float*)Av + (size_t)pairRow[p] * K;
  } else {
    int p = rowBase + tile0 + srow; p = p < NPAIR - 1 ? p : NPAIR - 1;
    aH = (const unsigned short*)Av + (size_t)p * K;
  }
  const size_t boff = (size_t)(col0 + srow) * K;

  f32x4 acc[4][4];
  f32x4 acc2[4][4];
  #pragma unroll
  for (int m = 0; m < 4; ++m)
    #pragma unroll
    for (int n = 0; n < 4; ++n) {
      acc[m][n] = f32x4{0.f, 0.f, 0.f, 0.f};
      if (SPLIT) acc2[m][n] = f32x4{0.f, 0.f, 0.f, 0.f};
    }

  for (int kt = 0; kt < K; kt += BK) {
    // stage A: fp32 -> fp16 level(s) in-register, ds_write fragment-order
    if (AMODE != 2) {
      #pragma unroll
      for (int it = 0; it < ISS; ++it) {
        const int u = it * 256 + tid;
        const int ko = kt + (u >> 7) * 8;
        const float* s;
        if (AMODE == 3) s = (ko < 512) ? (aP + ko) : (aR + (ko - 512));
        else            s = aF + ko;
        const float4 x0 = *(const float4*)s;
        const float4 x1 = *(const float4*)(s + 4);
        const float vv[8] = {x0.x, x0.y, x0.z, x0.w, x1.x, x1.y, x1.z, x1.w};
        f16x8 q0, q1;
        #pragma unroll
        for (int j = 0; j < 8; ++j) {
          const _Float16 c0 = (_Float16)vv[j];
          q0[j] = c0;
          if (SPLIT) q1[j] = (_Float16)((vv[j] - (float)c0) * 2048.f);
        }
        *(f16x8*)(sA0 + (size_t)u * 16) = q0;
        if (SPLIT) *(f16x8*)(sA1 + (size_t)u * 16) = q1;
      }
    }
    // stage B (and fp16 A) via async direct-to-LDS
    #pragma unroll
    for (int it = 0; it < ISS; ++it) {
      const int uo = (it * 256 + (tid & 192)) * 16;   // wave-uniform LDS base
      const int ko = kt + (it * 2 + (tid >> 7)) * 8;
      if (AMODE == 2) gl2lds(aH + ko, sA0 + uo);
      gl2lds(b0 + boff + ko, sB0 + uo);
      if (SPLIT) gl2lds(b1 + boff + ko, sB1 + uo);
    }
    __syncthreads();
    #pragma unroll
    for (int kk = 0; kk < NKK; ++kk) {
      const int g = kk * 4 + lg;
      f16x8 b0f[4], b1f[4];
      #pragma unroll
      for (int n = 0; n < 4; ++n) {
        const size_t off = (size_t)(g * 128 + wc + n * 16 + l15) * 16;
        b0f[n] = *(const f16x8*)(sB0 + off);
        if (SPLIT) b1f[n] = *(const f16x8*)(sB1 + off);
      }
      #pragma unroll
      for (int m = 0; m < 4; ++m) {
        const size_t ao = (size_t)(g * 128 + wr + m * 16 + l15) * 16;
        const f16x8 a0 = *(const f16x8*)(sA0 + ao);
        f16x8 a1;
        if (SPLIT) a1 = *(const f16x8*)(sA1 + ao);
        #pragma unroll
        for (int n = 0; n < 4; ++n) {
          if (SPLIT) {
            acc2[m][n] = __builtin_amdgcn_mfma_f32_16x16x32_f16(a1, b0f[n], acc2[m][n], 0, 0, 0);
            acc2[m][n] = __builtin_amdgcn_mfma_f32_16x16x32_f16(a0, b1f[n], acc2[m][n], 0, 0, 0);
          }
          acc[m][n] = __builtin_amdgcn_mfma_f32_16x16x32_f16(a0, b0f[n], acc[m][n], 0, 0, 0);
        }
      }
    }
    __syncthreads();
  }

  // epilogue. C/D mapping: col = lane&15, row = (lane>>4)*4 + j  [m89-verified]
  #pragma unroll
  for (int n = 0; n < 4; ++n) {
    const int cn = col0 + wc + n * 16 + l15;
    const float bv = bias[cn];
    #pragma unroll
    for (int m = 0; m < 4; ++m) {
      const int r0 = wr + m * 16 + ((lane >> 4) << 2);
      #pragma unroll
      for (int j = 0; j < 4; ++j) {
        const int rm = tile0 + r0 + j;
        if (EXPERT && rm >= Mloc) continue;
        float v = acc[m][n][j];
        if (SPLIT) v += acc2[m][n][j] * (1.f / 2048.f);
        v += bv;
        const size_t ci = (size_t)(EXPERT ? (rowBase + rm) : rm) * N + cn;
        if (EPI == 0) {
          Cf[ci] = v;
        } else if (EPI == 1) {
          Cb[ci] = f2h(fmaxf(v, 0.f));
        } else {
          Cb[ci] = f2h(v * pairW[rowBase + rm]);
        }
      }
    }
  }
}

// ---------------------------------------------------------------------------
// fp32 vector GEMM (gate + towers). C = relu(A@B[t] + bias[t]), fp32.
// ---------------------------------------------------------------------------
template<bool RELU>
__global__ __launch_bounds__(256, 2)
void gemm32_k(const float* __restrict__ Av, const float* __restrict__ Bb,
              const float* __restrict__ biasb, float* __restrict__ Cv,
              const int* __restrict__ taskPtr, int M, int N, int K)
{
  __shared__ float As[16][128];
  __shared__ float Bs[16][128];
  const int t = *taskPtr;
  const float* Bw = Bb + (size_t)t * K * N;
  const float* bias = biasb + (size_t)t * N;
  const int tile0 = blockIdx.x * 128;
  const int col0 = blockIdx.y * 128;
  const int tid = threadIdx.x;
  const int am = tid >> 1, ak = (tid & 1) * 8;
  const int bk = tid >> 4, bn = (tid & 15) * 8;
  const int rg = (tid >> 4) * 8, cg = (tid & 15) * 8;
  const float* aptr = Av + (size_t)(tile0 + am) * K;

  float acc[8][8];
  #pragma unroll
  for (int i = 0; i < 8; ++i)
    #pragma unroll
    for (int j = 0; j < 8; ++j) acc[i][j] = 0.f;

  for (int kt = 0; kt < K; kt += 16) {
    {
      const float* src = aptr + kt + ak;
      float4 x0 = *reinterpret_cast<const float4*>(src);
      float4 x1 = *reinterpret_cast<const float4*>(src + 4);
      As[ak+0][am]=x0.x; As[ak+1][am]=x0.y; As[ak+2][am]=x0.z; As[ak+3][am]=x0.w;
      As[ak+4][am]=x1.x; As[ak+5][am]=x1.y; As[ak+6][am]=x1.z; As[ak+7][am]=x1.w;
    }
    {
      const float* bsrc = Bw + (size_t)(kt + bk) * N + (col0 + bn);
      float4 b0 = *reinterpret_cast<const float4*>(bsrc);
      float4 b1 = *reinterpret_cast<const float4*>(bsrc + 4);
      Bs[bk][bn+0]=b0.x; Bs[bk][bn+1]=b0.y; Bs[bk][bn+2]=b0.z; Bs[bk][bn+3]=b0.w;
      Bs[bk][bn+4]=b1.x; Bs[bk][bn+5]=b1.y; Bs[bk][bn+6]=b1.z; Bs[bk][bn+7]=b1.w;
    }
    __syncthreads();
    #pragma unroll
    for (int k = 0; k < 16; ++k) {
      float4 a0 = *reinterpret_cast<const float4*>(&As[k][rg]);
      float4 a1 = *reinterpret_cast<const float4*>(&As[k][rg + 4]);
      float4 c0 = *reinterpret_cast<const float4*>(&Bs[k][cg]);
      float4 c1 = *reinterpret_cast<const float4*>(&Bs[k][cg + 4]);
      const float a[8] = {a0.x,a0.y,a0.z,a0.w,a1.x,a1.y,a1.z,a1.w};
      const float b[8] = {c0.x,c0.y,c0.z,c0.w,c1.x,c1.y,c1.z,c1.w};
      #pragma unroll
      for (int i = 0; i < 8; ++i)
        #pragma unroll
        for (int j = 0; j < 8; ++j)
          acc[i][j] = fmaf(a[i], b[j], acc[i][j]);
    }
    __syncthreads();
  }
  #pragma unroll
  for (int i = 0; i < 8; ++i) {
    const int mr = tile0 + rg + i;
    #pragma unroll
    for (int j = 0; j < 8; ++j) {
      float v = acc[i][j] + bias[col0 + cg + j];
      if (RELU) v = fmaxf(v, 0.f);
      Cv[(size_t)mr * N + col0 + cg + j] = v;
    }
  }
}

// ---------------------------------------------------------------------------
// transpose+convert: src fp32 [z][R][C] -> fp16 level arrays [z][C][R].
// LEV=2: level-1 stored x2048 (scaled split, matches mgemm epilogue).
// ---------------------------------------------------------------------------
template<int LEV>
__global__ __launch_bounds__(256)
void transp_k(const float* __restrict__ src, unsigned short* __restrict__ d0,
              unsigned short* __restrict__ d1, int R, int C)
{
  __shared__ float tle[32][33];
  const size_t bb = (size_t)blockIdx.z * R * C;
  const int r0 = blockIdx.x * 32, c0 = blockIdx.y * 32;
  const int x = threadIdx.x & 31, y = threadIdx.x >> 5;
  #pragma unroll
  for (int i = 0; i < 32; i += 8)
    tle[y + i][x] = src[bb + (size_t)(r0 + y + i) * C + (c0 + x)];
  __syncthreads();
  #pragma unroll
  for (int i = 0; i < 32; i += 8) {
    const float v = tle[x][y + i];
    const size_t di = bb + (size_t)(c0 + y + i) * R + (r0 + x);
    const unsigned short h0 = f2h(v);
    d0[di] = h0;
    if (LEV > 1) d1[di] = f2h((v - h2f(h0)) * 2048.f);
  }
}

// ---------------------------------------------------------------------------
// In-place LayerNorm (+ optional relu) over fp32 rows of COLS.
// ---------------------------------------------------------------------------
template<int COLS, bool RELU>
__global__ __launch_bounds__(256)
void ln_k(float* __restrict__ x, const float* __restrict__ g, const float* __restrict__ b)
{
  constexpr int PER = COLS / 256;
  const size_t row = blockIdx.x;
  float* xr = x + row * COLS;
  float v[PER];
  float s = 0.f, s2 = 0.f;
  #pragma unroll
  for (int i = 0; i < PER; ++i) {
    v[i] = xr[threadIdx.x + i * 256];
    s += v[i];
    s2 += v[i] * v[i];
  }
  #pragma unroll
  for (int o = 1; o < 64; o <<= 1) { s += __shfl_xor(s, o); s2 += __shfl_xor(s2, o); }
  __shared__ float ss[4], ss2[4];
  const int w = threadIdx.x >> 6;
  if ((threadIdx.x & 63) == 0) { ss[w] = s; ss2[w] = s2; }
  __syncthreads();
  s  = ss[0] + ss[1] + ss[2] + ss[3];
  s2 = ss2[0] + ss2[1] + ss2[2] + ss2[3];
  const float mu = s * (1.f / COLS);
  const float var = s2 * (1.f / COLS) - mu * mu;
  const float rs = rsqrtf(var + 1e-5f);
  #pragma unroll
  for (int i = 0; i < PER; ++i) {
    const int c = threadIdx.x + i * 256;
    float y = (v[i] - mu) * rs * g[c] + b[c];
    if (RELU) y = fmaxf(y, 0.f);
    xr[c] = y;
  }
}

// ---------------------------------------------------------------------------
// gate: logits = relu-g @ gW2[t] + gb2[t]; top-3 softmax; NO global atomics.
// ---------------------------------------------------------------------------
__global__ __launch_bounds__(256)
void gate_topk_k(const float* __restrict__ g, const float* __restrict__ gW2,
                 const float* __restrict__ gb2, const int* __restrict__ taskPtr,
                 float* __restrict__ gatesOut, int* __restrict__ topkIdx,
                 float* __restrict__ topkW)
{
  const int t = *taskPtr;
  const float* W = gW2 + (size_t)t * 128 * 16;
  const float* bias = gb2 + (size_t)t * 16;
  const int lane = threadIdx.x & 63;
  const int row = blockIdx.x * 4 + (threadIdx.x >> 6);
  const float* gr = g + (size_t)row * 128;
  const int e = lane & 15;
  const int q = lane >> 4;
  float s = 0.f;
  for (int j = q * 32; j < q * 32 + 32; ++j) s = fmaf(gr[j], W[j * 16 + e], s);
  s += __shfl_xor(s, 16);
  s += __shfl_xor(s, 32);
  s += bias[e];
  float logits[16];
  #pragma unroll
  for (int i = 0; i < 16; ++i) logits[i] = __shfl(s, i);
  int i0 = 0; float v0 = logits[0];
  #pragma unroll
  for (int i = 1; i < 16; ++i) if (logits[i] > v0) { v0 = logits[i]; i0 = i; }
  int i1 = -1; float v1 = -3.4e38f;
  #pragma unroll
  for (int i = 0; i < 16; ++i) if (i != i0 && logits[i] > v1) { v1 = logits[i]; i1 = i; }
  int i2 = -1; float v2 = -3.4e38f;
  #pragma unroll
  for (int i = 0; i < 16; ++i) if (i != i0 && i != i1 && logits[i] > v2) { v2 = logits[i]; i2 = i; }
  const float ex1 = expf(v1 - v0);
  const float ex2 = expf(v2 - v0);
  const float inv = 1.f / (1.f + ex1 + ex2);
  const float p0 = inv, p1 = ex1 * inv, p2 = ex2 * inv;
  if (lane < 16) {
    const float gv = (lane == i0) ? p0 : (lane == i1) ? p1 : (lane == i2) ? p2 : 0.f;
    gatesOut[(size_t)row * 16 + lane] = gv;
  }
  if (lane == 0) {
    topkIdx[row * 3 + 0] = i0; topkIdx[row * 3 + 1] = i1; topkIdx[row * 3 + 2] = i2;
    topkW [row * 3 + 0] = p0; topkW [row * 3 + 1] = p1; topkW [row * 3 + 2] = p2;
  }
}

// per-chunk expert histogram (LDS atomics only)
__global__ __launch_bounds__(256)
void hist_k(const int* __restrict__ topkIdx, int* __restrict__ chunkCnt)
{
  __shared__ int lc[NEXP];
  if (threadIdx.x < NEXP) lc[threadIdx.x] = 0;
  __syncthreads();
  const int row = blockIdx.x * 256 + threadIdx.x;
  #pragma unroll
  for (int k = 0; k < 3; ++k) atomicAdd(&lc[topkIdx[row * 3 + k]], 1);
  __syncthreads();
  if (threadIdx.x < NEXP) chunkCnt[blockIdx.x * NEXP + threadIdx.x] = lc[threadIdx.x];
}

// serial scan: counts/offs per expert + per-chunk bases
__global__ void scanB_k(const int* __restrict__ chunkCnt, int* __restrict__ counts,
                        int* __restrict__ offs, int* __restrict__ chunkBase)
{
  if (threadIdx.x == 0) {
    int tot[NEXP];
    for (int e = 0; e < NEXP; ++e) tot[e] = 0;
    for (int c = 0; c < 64; ++c)
      for (int e = 0; e < NEXP; ++e) tot[e] += chunkCnt[c * NEXP + e];
    int a = 0;
    for (int e = 0; e < NEXP; ++e) { offs[e] = a; counts[e] = tot[e]; a += tot[e]; }
    for (int e = 0; e < NEXP; ++e) {
      int b = offs[e];
      for (int c = 0; c < 64; ++c) { chunkBase[c * NEXP + e] = b; b += chunkCnt[c * NEXP + e]; }
    }
  }
}

// fill pair lists: LDS-atomic within-chunk offsets + precomputed chunk base
__global__ __launch_bounds__(256)
void fill2_k(const int* __restrict__ topkIdx, const float* __restrict__ topkW,
             const int* __restrict__ chunkBase, int* __restrict__ pairRow,
             float* __restrict__ pairW, int* __restrict__ rowPos)
{
  __shared__ int lc[NEXP];
  if (threadIdx.x < NEXP) lc[threadIdx.x] = 0;
  __syncthreads();
  const int row = blockIdx.x * 256 + threadIdx.x;
  #pragma unroll
  for (int k = 0; k < 3; ++k) {
    const int e = topkIdx[row * 3 + k];
    const int lofs = atomicAdd(&lc[e], 1);
    const int pos = chunkBase[blockIdx.x * NEXP + e] + lofs;
    pairRow[pos] = row;
    pairW[pos] = topkW[row * 3 + k];
    rowPos[row * 3 + k] = pos;
  }
}

__global__ __launch_bounds__(256)
void mixreduce_k(const unsigned short* __restrict__ eo, const int* __restrict__ rowPos,
                 float* __restrict__ mix)
{
  const size_t row = blockIdx.x;
  const size_t p0 = rowPos[row * 3 + 0];
  const size_t p1 = rowPos[row * 3 + 1];
  const size_t p2 = rowPos[row * 3 + 2];
  for (int c = threadIdx.x; c < EXPSZ; c += 256) {
    mix[row * EXPSZ + c] = h2f(eo[p0 * EXPSZ + c]) + h2f(eo[p1 * EXPSZ + c])
                         + h2f(eo[p2 * EXPSZ + c]);
  }
}

__global__ __launch_bounds__(256)
void tower3_k(const float* __restrict__ t2, const float* __restrict__ tW3,
              const float* __restrict__ tb3, const int* __restrict__ taskPtr,
              float* __restrict__ out)
{
  const int t = *taskPtr;
  const float* w = tW3 + (size_t)t * 128;
  const float bias = tb3[t];
  const int lane = threadIdx.x & 63;
  const int row = blockIdx.x * 4 + (threadIdx.x >> 6);
  const float* x = t2 + (size_t)row * 128;
  float s = fmaf(x[lane], w[lane], x[lane + 64] * w[lane + 64]);
  #pragma unroll
  for (int o = 1; o < 64; o <<= 1) s += __shfl_xor(s, o);
  if (lane == 0) out[row] = 1.f / (1.f + expf(-(s + bias)));
  if (blockIdx.x == 0 && threadIdx.x == 0) out[BATCH] = (float)t;
}

// ---------------------------------------------------------------------------
extern "C" void kernel_launch(void* const* d_in, const int* in_sizes, int n_in,
                              void* d_out, int out_size, void* d_ws, size_t ws_size,
                              hipStream_t stream)
{
  (void)in_sizes; (void)n_in; (void)out_size; (void)ws_size;
  const float* embP  = (const float*)d_in[0];
  const float* embR  = (const float*)d_in[1];
  const float* encW1 = (const float*)d_in[2];
  const float* encB1 = (const float*)d_in[3];
  const float* ln1g  = (const float*)d_in[4];
  const float* ln1b  = (const float*)d_in[5];
  const float* encW2 = (const float*)d_in[6];
  const float* encB2 = (const float*)d_in[7];
  const float* ln2g  = (const float*)d_in[8];
  const float* ln2b  = (const float*)d_in[9];
  const float* gW1   = (const float*)d_in[10];
  const float* gb1   = (const float*)d_in[11];
  const float* gW2   = (const float*)d_in[12];
  const float* gb2   = (const float*)d_in[13];
  const float* We1   = (const float*)d_in[14];
  const float* be1   = (const float*)d_in[15];
  const float* We2   = (const float*)d_in[16];
  const float* be2   = (const float*)d_in[17];
  const float* tW1   = (const float*)d_in[18];
  const float* tb1   = (const float*)d_in[19];
  const float* tW2   = (const float*)d_in[20];
  const float* tb2   = (const float*)d_in[21];
  const float* tW3   = (const float*)d_in[22];
  const float* tb3   = (const float*)d_in[23];
  const int* taskPtr = (const int*)d_in[24];

  float* out = (float*)d_out;
  char* ws = (char*)d_ws;
  const size_t MB = 1ull << 20;

  // Lifetime-aliased workspace (peak ~209 MB):
  //  [0,64):    feat fp32 -> mix[0,32), t1[32,48), t2[48,56)
  //  [64,192):  h fp32 -> We1t0[64,80), We2t0[80,88), e1[88,136), eo[136,184)
  //  [192,208): W1t0/W1t1/W2t0/W2t1 (4MB each) -> gbuf[192,200)
  //  [208,~209): metadata
  float* feat = (float*)(ws);
  float* mix  = (float*)(ws);
  float* t1   = (float*)(ws + 32 * MB);
  float* t2v  = (float*)(ws + 48 * MB);
  float* h    = (float*)(ws + 64 * MB);
  unsigned short* We1t0 = (unsigned short*)(ws + 64 * MB);
  unsigned short* We2t0 = (unsigned short*)(ws + 80 * MB);
  unsigned short* e1b   = (unsigned short*)(ws + 88 * MB);
  unsigned short* eob   = (unsigned short*)(ws + 136 * MB);
  unsigned short* W1t0  = (unsigned short*)(ws + 192 * MB);
  unsigned short* W1t1  = (unsigned short*)(ws + 196 * MB);
  unsigned short* W2t0  = (unsigned short*)(ws + 200 * MB);
  unsigned short* W2t1  = (unsigned short*)(ws + 204 * MB);
  float* gbuf = (float*)(ws + 192 * MB);
  char* small = ws + 208 * MB;
  int*   counts    = (int*)  (small);
  int*   offs      = (int*)  (small + 1024);
  int*   chunkCnt  = (int*)  (small + 2048);
  int*   chunkBase = (int*)  (small + 2048 + 4096);
  int*   topkIdx   = (int*)  (small + 16384);
  float* topkW     = (float*)(small + 16384 + 196608);
  int*   pairRow   = (int*)  (small + 16384 + 2 * 196608);
  float* pairW     = (float*)(small + 16384 + 3 * 196608);
  int*   rowPos    = (int*)  (small + 16384 + 4 * 196608);

  const dim3 blk(256, 1, 1);

  // encoder GEMM1: h = concat(embP,embR) @ W1 + b1  (fp16 2-lev split, 3 terms)
  transp_k<2><<<dim3(DIN/32, DHID/32, 1), blk, 0, stream>>>(encW1, W1t0, W1t1, DIN, DHID);
  mgemm_k<1,3,0,32><<<dim3(BATCH/128, DHID/128, 1), blk, 0, stream>>>(
      embP, embR, W1t0, W1t1, encB1, h, nullptr,
      nullptr, nullptr, nullptr, nullptr, BATCH, DHID, DIN);
  ln_k<DHID, true><<<dim3(BATCH, 1, 1), blk, 0, stream>>>(h, ln1g, ln1b);

  // encoder GEMM2: feat = h @ W2 + b2  (fp16 2-lev split, 3 terms)
  transp_k<2><<<dim3(DHID/32, DIN/32, 1), blk, 0, stream>>>(encW2, W2t0, W2t1, DHID, DIN);
  mgemm_k<1,0,0,32><<<dim3(BATCH/128, DIN/128, 1), blk, 0, stream>>>(
      h, nullptr, W2t0, W2t1, encB2, feat, nullptr,
      nullptr, nullptr, nullptr, nullptr, BATCH, DIN, DHID);
  ln_k<DIN, false><<<dim3(BATCH, 1, 1), blk, 0, stream>>>(feat, ln2g, ln2b);

  // gate (fp32 vector path on fp32 feat) — no global atomics anywhere
  gemm32_k<true><<<dim3(BATCH/128, 1, 1), blk, 0, stream>>>(
      feat, gW1, gb1, gbuf, taskPtr, BATCH, 128, DIN);
  gate_topk_k<<<dim3(BATCH/4, 1, 1), blk, 0, stream>>>(
      gbuf, gW2, gb2, taskPtr, out + BATCH + 1, topkIdx, topkW);
  hist_k<<<dim3(BATCH/256, 1, 1), blk, 0, stream>>>(topkIdx, chunkCnt);
  scanB_k<<<dim3(1, 1, 1), dim3(64, 1, 1), 0, stream>>>(chunkCnt, counts, offs, chunkBase);
  fill2_k<<<dim3(BATCH/256, 1, 1), blk, 0, stream>>>(topkIdx, topkW, chunkBase,
                                                     pairRow, pairW, rowPos);

  // expert weights, single fp16 level (h region free now)
  transp_k<1><<<dim3(DIN/32, EXPSZ/32, NEXP), blk, 0, stream>>>(We1, We1t0, nullptr, DIN, EXPSZ);
  transp_k<1><<<dim3(EXPSZ/32, EXPSZ/32, NEXP), blk, 0, stream>>>(We2, We2t0, nullptr, EXPSZ, EXPSZ);

  // expert GEMM1: e1 = relu(feat[pairRow] @ We1[e] + be1)  (plain fp16)
  mgemm_k<0,1,1,64><<<dim3(BATCH/128, EXPSZ/128, NEXP), blk, 0, stream>>>(
      feat, nullptr, We1t0, nullptr, be1, nullptr, e1b,
      pairRow, nullptr, counts, offs, NPAIR, EXPSZ, DIN);
  // expert GEMM2: eo = w_p * (e1 @ We2[e] + be2)  (plain fp16)
  mgemm_k<0,2,2,64><<<dim3(BATCH/128, EXPSZ/128, NEXP), blk, 0, stream>>>(
      e1b, nullptr, We2t0, nullptr, be2, nullptr, eob,
      nullptr, pairW, counts, offs, NPAIR, EXPSZ, EXPSZ);
  mixreduce_k<<<dim3(BATCH, 1, 1), blk, 0, stream>>>(eob, rowPos, mix);

  // towers (fp32)
  gemm32_k<true><<<dim3(BATCH/128, 2, 1), blk, 0, stream>>>(
      mix, tW1, tb1, t1, taskPtr, BATCH, 256, EXPSZ);
  gemm32_k<true><<<dim3(BATCH/128, 1, 1), blk, 0, stream>>>(
      t1, tW2, tb2, t2v, taskPtr, BATCH, 128, 256);
  tower3_k<<<dim3(BATCH/4, 1, 1), blk, 0, stream>>>(t2v, tW3, tb3, taskPtr, out);
}